// Round 8
// baseline (178.918 us; speedup 1.0000x reference)
//
#include <hip/hip_runtime.h>
#include <stdint.h>

// Fused MLP decode, MFMA f16. Wave = 64 points (4 sub-tiles of 16).
// 2-wave workgroups, ZERO barriers (wave-private LDS, in-order DS pipe).
// R8: software-pipelined emb gathers (next sub-tile's load issued before
// current compute; next group's tix/rho prefetched at loop top) and
// pair-reciprocal silu (1 v_rcp per 2 sigmoids).
// NOTE: __launch_bounds__ has NO min-waves arg — ",4" forced a 64-VGPR
// target and ~600MB/dispatch scratch spills (R3/R4). Needs ~120 VGPRs.

typedef _Float16 half8  __attribute__((ext_vector_type(8)));
typedef _Float16 half4v __attribute__((ext_vector_type(4)));
typedef _Float16 half2v __attribute__((ext_vector_type(2)));
typedef float f32x4 __attribute__((ext_vector_type(4)));

#define LOG2E 1.44269504088896340736f
#define BASE_LOGIT -0.84729786038720367f   // log(0.3/0.7)
#define CSANMAX 28700.0f
#define IC_VAL 8610.0f                     // 0.3 * 28700

__device__ __forceinline__ float fast_exp2(float x) { return __builtin_amdgcn_exp2f(x); }
__device__ __forceinline__ float fast_rcp(float x)  { return __builtin_amdgcn_rcpf(x); }
__device__ __forceinline__ float sigf(float x)  { return fast_rcp(1.0f + fast_exp2(-LOG2E * x)); }
// pair silu: one rcp serves two sigmoids (r=rcp(d0*d1); sig0=d1*r; sig1=d0*r)
__device__ __forceinline__ void silu2(float x0, float x1, float& y0, float& y1) {
  const float d0 = 1.0f + fast_exp2(-LOG2E * x0);
  const float d1 = 1.0f + fast_exp2(-LOG2E * x1);
  const float r  = fast_rcp(d0 * d1);
  y0 = x0 * d1 * r;
  y1 = x1 * d0 * r;
}
__device__ __forceinline__ half2v pkh(float a, float b) {
  return __builtin_bit_cast(half2v, __builtin_amdgcn_cvt_pkrtz(a, b));
}

union H8 { half8 v8; half2v v2[4]; };
union H4 { half4v v4; half2v v2[2]; };

template <int CTRL>
__device__ __forceinline__ float dpp_radd(float x) {
  int yi = __builtin_amdgcn_update_dpp(0, __builtin_bit_cast(int, x), CTRL, 0xF, 0xF, false);
  return x + __builtin_bit_cast(float, yi);
}
// sum across the 16 lanes of a DPP row (our q-group); result in all 16 lanes
__device__ __forceinline__ float row_sum16(float x) {
  x = dpp_radd<0xB1>(x);    // quad_perm [1,0,3,2]
  x = dpp_radd<0x4E>(x);    // quad_perm [2,3,0,1]
  x = dpp_radd<0x141>(x);   // row_half_mirror
  x = dpp_radd<0x140>(x);   // row_mirror
  return x;
}

__global__ __launch_bounds__(128) void mlp_kernel(
    const int* __restrict__ tix, const float* __restrict__ rho,
    const float* __restrict__ emb, const float* __restrict__ W0,
    const float* __restrict__ b0, const float* __restrict__ W1,
    const float* __restrict__ b1, const float* __restrict__ Wout,
    const float* __restrict__ bout, float* __restrict__ out, int ngroups)
{
  // per-wave regions: F stride 40 halfs (80B), H stride 72 halfs (144B).
  __shared__ __align__(16) _Float16 ldsF[2][64][40];
  __shared__ __align__(16) _Float16 ldsH[2][2][16][72];

  const int tid  = threadIdx.x;
  const int wid  = tid >> 6;
  const int lane = tid & 63;
  const int m    = lane & 15;
  const int q    = lane >> 4;

  _Float16 (*F)[40]      = ldsF[wid];
  _Float16 (*Hd)[16][72] = ldsH[wid];

  // ---- one-time: weight fragments (72 persistent VGPRs) ----
  // content B[k=s*32+q*8+j][n=t*16+m]; A-op for L0 (=> W^T), B-op for L1.
  half8 B0f[4][2], B1f[4][2];
#pragma unroll
  for (int t = 0; t < 4; ++t) {
#pragma unroll
    for (int s = 0; s < 2; ++s) {
      half8 f0, f1;
#pragma unroll
      for (int j = 0; j < 8; ++j) {
        const int k = s * 32 + q * 8 + j;
        const int n = t * 16 + m;
        // pad K 49->64; fold b0 into k==49 (feature there is 1.0)
        const float v0 = (k < 49) ? W0[k * 64 + n] : ((k == 49) ? b0[n] : 0.0f);
        f0[j] = (_Float16)v0;
        f1[j] = (_Float16)W1[k * 64 + n];
      }
      B0f[t][s] = f0;
      B1f[t][s] = f1;
    }
  }
  float b1n[4], woutm[4];
#pragma unroll
  for (int t = 0; t < 4; ++t) {
    b1n[t]   = b1[t * 16 + m];
    woutm[t] = Wout[t * 16 + m];
  }
  const float boutBL = bout[0] + BASE_LOGIT;

  // one-time: zero the constant K-pad cols 18..31 (16..17 rewritten per group)
  {
    half8 zc = (half8)(_Float16)0.0f;
    *(half8*)&F[lane][16] = zc;
    *(half8*)&F[lane][24] = zc;
  }

  const f32x4 z = {0.0f, 0.0f, 0.0f, 0.0f};
  const int gwaves = gridDim.x * 2;

  int g = blockIdx.x * 2 + wid;
  if (g >= ngroups) return;   // safe: no barriers anywhere

  // pre-loop: first group's point data
  int   tiL = tix[g * 64 + lane];
  float rh  = rho[g * 64 + lane];

  for (; g < ngroups; g += gwaves) {
    const int gbase = g * 64;

    // ---- prefetch next group's point data (hides ~400cyc at next loop top) ----
    const int gn = (g + gwaves < ngroups) ? (g + gwaves) : g;
    const int   tiLn = tix[gn * 64 + lane];
    const float rhn  = rho[gn * 64 + lane];

    // ---- gather pipeline: all 4 sub-tile indices now; issue st=0 load ----
    int tim4[4];
#pragma unroll
    for (int st = 0; st < 4; ++st) tim4[st] = __shfl(tiL, st * 16 + m, 64);
    const float* erow0 = emb + (size_t)min(max(tim4[0] - 1, 0), 510) * 32 + q * 8;
    f32x4 eA0 = *(const f32x4*)erow0;
    f32x4 eA1 = *(const f32x4*)(erow0 + 4);

    // ---- P1: Fourier features (Chebyshev), overlaps st0 gather ----
    const float rev = 0.5f * rh;           // v_sin/v_cos take revolutions
    const float c1 = __builtin_amdgcn_cosf(rev);
    const float s1 = __builtin_amdgcn_sinf(rev);
    float cs[8], sn[8];
    cs[0] = c1; sn[0] = s1;
    {
      float cm2 = 1.0f, cm1 = c1, sm2 = 0.0f, sm1 = s1;
      const float tc = 2.0f * c1;
#pragma unroll
      for (int k = 1; k < 8; ++k) {
        const float ck = tc * cm1 - cm2;
        const float sk = tc * sm1 - sm2;
        cs[k] = ck; sn[k] = sk;
        cm2 = cm1; cm1 = ck; sm2 = sm1; sm1 = sk;
      }
    }
    // F row: [rho, c1..c7 | c8, s1..s7 | s8, 1.0, 0 x14 | pad]
    H8 h0, h1;
    h0.v2[0] = pkh(rh,    cs[0]); h0.v2[1] = pkh(cs[1], cs[2]);
    h0.v2[2] = pkh(cs[3], cs[4]); h0.v2[3] = pkh(cs[5], cs[6]);
    h1.v2[0] = pkh(cs[7], sn[0]); h1.v2[1] = pkh(sn[1], sn[2]);
    h1.v2[2] = pkh(sn[3], sn[4]); h1.v2[3] = pkh(sn[5], sn[6]);
    *(half8*)&F[lane][0] = h0.v8;
    *(half8*)&F[lane][8] = h1.v8;
    *(half2v*)&F[lane][16] = pkh(sn[7], 1.0f);
    // no barrier: same-wave DS ops are in-order

    float dcar = 0.0f;  // carried raw output dot for point gbase+lane

#pragma unroll
    for (int st = 0; st < 4; ++st) {
      _Float16 (*Hb)[72] = Hd[st & 1];

      // issue next sub-tile's emb gather BEFORE this sub-tile's compute
      f32x4 eB0, eB1;
      if (st < 3) {
        const float* erown = emb + (size_t)min(max(tim4[st + 1] - 1, 0), 510) * 32 + q * 8;
        eB0 = *(const f32x4*)erown;
        eB1 = *(const f32x4*)(erown + 4);
      }

      // ---- L0 (transposed): D = W0^T · X^T ----
      H8 X0;
      X0.v2[0] = pkh(eA0[0], eA0[1]); X0.v2[1] = pkh(eA0[2], eA0[3]);
      X0.v2[2] = pkh(eA1[0], eA1[1]); X0.v2[3] = pkh(eA1[2], eA1[3]);
      const half8 X1 = *(const half8*)&F[st * 16 + m][q * 8];

      f32x4 acc[4];
#pragma unroll
      for (int t = 0; t < 4; ++t) {
        f32x4 a = __builtin_amdgcn_mfma_f32_16x16x32_f16(B0f[t][0], X0.v8, z, 0, 0, 0);
        a = __builtin_amdgcn_mfma_f32_16x16x32_f16(B0f[t][1], X1, a, 0, 0, 0);
        acc[t] = a;
      }
      // epilogue: lane(m,q) reg r = preact[hidden=t*16+q*4+r][point=st*16+m]
#pragma unroll
      for (int t = 0; t < 4; ++t) {
        float s0, s1v, s2, s3;
        silu2(acc[t][0], acc[t][1], s0, s1v);
        silu2(acc[t][2], acc[t][3], s2, s3);
        H4 hh;
        hh.v2[0] = pkh(s0, s1v);
        hh.v2[1] = pkh(s2, s3);
        *(half4v*)&Hb[m][t * 16 + q * 4] = hh.v4;
      }

      // ---- L1 (untransposed): D = h1 · W1 + b1 (b1 via C-init) ----
      const half8 Y0 = *(const half8*)&Hb[m][q * 8];        // in-order DS: RAW safe
      const half8 Y1 = *(const half8*)&Hb[m][32 + q * 8];
#pragma unroll
      for (int t = 0; t < 4; ++t) {
        const f32x4 binit = {b1n[t], b1n[t], b1n[t], b1n[t]};
        f32x4 a = __builtin_amdgcn_mfma_f32_16x16x32_f16(Y0, B1f[t][0], binit, 0, 0, 0);
        a = __builtin_amdgcn_mfma_f32_16x16x32_f16(Y1, B1f[t][1], a, 0, 0, 0);
        acc[t] = a;
      }
      // C[point=q*4+r][hidden=t*16+m]: fuse silu + Wout dot in regs
      float dot0 = 0.0f, dot1 = 0.0f, dot2 = 0.0f, dot3 = 0.0f;
#pragma unroll
      for (int t = 0; t < 4; ++t) {
        float s0, s1v, s2, s3;
        silu2(acc[t][0], acc[t][1], s0, s1v);
        silu2(acc[t][2], acc[t][3], s2, s3);
        dot0 = fmaf(s0,  woutm[t], dot0);
        dot1 = fmaf(s1v, woutm[t], dot1);
        dot2 = fmaf(s2,  woutm[t], dot2);
        dot3 = fmaf(s3,  woutm[t], dot3);
      }
      // reduce over the 16 m-lanes of each q-row (DPP, VALU pipe)
      dot0 = row_sum16(dot0);
      dot1 = row_sum16(dot1);
      dot2 = row_sum16(dot2);
      dot3 = row_sum16(dot3);
      // route: value for point st*16+m lives as dots[m&3] in row (m>>2)
      const float dsel = (m & 2) ? ((m & 1) ? dot3 : dot2) : ((m & 1) ? dot1 : dot0);
      const float dg = __shfl(dsel, (m >> 2) * 16 + (m & 3), 64);
      dcar = (q == st) ? dg : dcar;

      eA0 = eB0; eA1 = eB1;  // rotate gather pipeline (dead on st==3)
    }

    // ---- epilogue: one coalesced 256B store per group ----
    const float theta = sigf(dcar + boutBL);
    out[gbase + lane] = (tiL == 0) ? IC_VAL : theta * CSANMAX;

    tiL = tiLn; rh = rhn;  // rotate group-level prefetch
  }
}

extern "C" void kernel_launch(void* const* d_in, const int* in_sizes, int n_in,
                              void* d_out, int out_size, void* d_ws, size_t ws_size,
                              hipStream_t stream) {
  const int*   tix  = (const int*)d_in[0];
  const float* rho  = (const float*)d_in[1];
  const float* emb  = (const float*)d_in[2];
  const float* W0   = (const float*)d_in[3];
  const float* b0   = (const float*)d_in[4];
  const float* W1   = (const float*)d_in[5];
  const float* b1   = (const float*)d_in[6];
  const float* Wout = (const float*)d_in[7];
  const float* bout = (const float*)d_in[8];
  float* outp = (float*)d_out;

  const int n       = in_sizes[0];   // 2,000,000 (divisible by 64)
  const int ngroups = n / 64;        // 31,250 groups of 64 points

  int grid = 2048;                   // 2-wave blocks: 4096 waves, 8 blocks/CU
  if (grid * 2 > ngroups) grid = (ngroups + 1) / 2;
  mlp_kernel<<<dim3(grid), dim3(128), 0, stream>>>(
      tix, rho, emb, W0, b0, W1, b1, Wout, bout, outp, ngroups);
}

// Round 9
// 174.789 us; speedup vs baseline: 1.0236x; 1.0236x over previous
//
#include <hip/hip_runtime.h>
#include <stdint.h>

// Fused MLP decode, MFMA f16. Wave = 64 points (4 sub-tiles of 16).
// 4-wave workgroups. Weights live in workgroup-shared LDS, pre-swizzled in
// fragment order (lane*16B contiguous ds_read_b128) -> frees ~64 VGPRs for
// occupancy (target 6 waves/SIMD). Layer-0 feature fragments are generated
// directly in MFMA A-layout per sub-tile via a single Chebyshev chain
// (features reordered [c1..c8|s1..s8|rho,1,0..]; W0 rows permuted to match).
// Single-buffered H (per-wave): the DS pipe is in-order within a wave, so
// write-after-read across sub-tiles is safe with NO barriers in the loop.
// NOTE: __launch_bounds__ has NO min-waves arg — ",4" forced a 64-VGPR
// target and ~600MB/dispatch scratch spills (R3/R4).

typedef _Float16 half8  __attribute__((ext_vector_type(8)));
typedef _Float16 half4v __attribute__((ext_vector_type(4)));
typedef _Float16 half2v __attribute__((ext_vector_type(2)));
typedef float f32x4 __attribute__((ext_vector_type(4)));

#define LOG2E 1.44269504088896340736f
#define BASE_LOGIT -0.84729786038720367f   // log(0.3/0.7)
#define CSANMAX 28700.0f
#define IC_VAL 8610.0f                     // 0.3 * 28700

__device__ __forceinline__ float fast_exp2(float x) { return __builtin_amdgcn_exp2f(x); }
__device__ __forceinline__ float fast_rcp(float x)  { return __builtin_amdgcn_rcpf(x); }
__device__ __forceinline__ float sigf(float x)  { return fast_rcp(1.0f + fast_exp2(-LOG2E * x)); }
// pair silu: one rcp serves two sigmoids
__device__ __forceinline__ void silu2(float x0, float x1, float& y0, float& y1) {
  const float d0 = 1.0f + fast_exp2(-LOG2E * x0);
  const float d1 = 1.0f + fast_exp2(-LOG2E * x1);
  const float r  = fast_rcp(d0 * d1);
  y0 = x0 * d1 * r;
  y1 = x1 * d0 * r;
}
__device__ __forceinline__ half2v pkh(float a, float b) {
  return __builtin_bit_cast(half2v, __builtin_amdgcn_cvt_pkrtz(a, b));
}

union H8 { half8 v8; half2v v2[4]; };
union H4 { half4v v4; half2v v2[2]; };

template <int CTRL>
__device__ __forceinline__ float dpp_radd(float x) {
  int yi = __builtin_amdgcn_update_dpp(0, __builtin_bit_cast(int, x), CTRL, 0xF, 0xF, false);
  return x + __builtin_bit_cast(float, yi);
}
// sum across the 16 lanes of a DPP row; result in all 16 lanes
__device__ __forceinline__ float row_sum16(float x) {
  x = dpp_radd<0xB1>(x);    // quad_perm [1,0,3,2]
  x = dpp_radd<0x4E>(x);    // quad_perm [2,3,0,1]
  x = dpp_radd<0x141>(x);   // row_half_mirror
  x = dpp_radd<0x140>(x);   // row_mirror
  return x;
}

__global__ __launch_bounds__(256) void mlp_kernel(
    const int* __restrict__ tix, const float* __restrict__ rho,
    const float* __restrict__ emb, const float* __restrict__ W0,
    const float* __restrict__ b0, const float* __restrict__ W1,
    const float* __restrict__ b1, const float* __restrict__ Wout,
    const float* __restrict__ bout, float* __restrict__ out, int ngroups)
{
  // Weights: fragment-order swizzle [s][t][lane][8 f16] -> 8 KB per layer.
  __shared__ __align__(16) _Float16 Wlds0[2][4][64][8];
  __shared__ __align__(16) _Float16 Wlds1[2][4][64][8];
  // H: per-wave single buffer, stride 72 halfs (144 B).
  __shared__ __align__(16) _Float16 ldsH[4][16][72];

  const int tid  = threadIdx.x;
  const int wid  = tid >> 6;
  const int lane = tid & 63;
  const int m    = lane & 15;
  const int q    = lane >> 4;

  _Float16 (*Hb)[72] = ldsH[wid];

  // ---- init: wave 0 builds the swizzled weight fragments ----
  // content B[k=s*32+q*8+j][n=t*16+m]; A-op for L0 (=> W^T), B-op for L1.
  // Layer-0 feature rows PERMUTED: input k-window 32..63 maps to
  // [cos1..8 | sin1..8 | rho, b0-slot(1.0), 0-pad]:
  //   kn=k-32: kn<16 -> W0 row 33+kn ; kn==16 -> row 32 (rho) ; kn==17 -> b0 ; else 0.
  if (wid == 0) {
#pragma unroll
    for (int t = 0; t < 4; ++t) {
#pragma unroll
      for (int s = 0; s < 2; ++s) {
        half8 f0, f1;
#pragma unroll
        for (int j = 0; j < 8; ++j) {
          const int k = s * 32 + q * 8 + j;
          const int n = t * 16 + m;
          float v0;
          if (k < 32) {
            v0 = W0[k * 64 + n];
          } else {
            const int kn = k - 32;
            v0 = (kn < 16) ? W0[(33 + kn) * 64 + n]
               : (kn == 16) ? W0[32 * 64 + n]
               : (kn == 17) ? b0[n] : 0.0f;
          }
          f0[j] = (_Float16)v0;
          f1[j] = (_Float16)W1[k * 64 + n];
        }
        *(half8*)&Wlds0[s][t][lane][0] = f0;
        *(half8*)&Wlds1[s][t][lane][0] = f1;
      }
    }
  }

  float b1n[4], woutm[4];
#pragma unroll
  for (int t = 0; t < 4; ++t) {
    b1n[t]   = b1[t * 16 + m];
    woutm[t] = Wout[t * 16 + m];
  }
  const float boutBL = bout[0] + BASE_LOGIT;

  __syncthreads();   // weights visible to all 4 waves (only barrier in kernel)

  const f32x4 z = {0.0f, 0.0f, 0.0f, 0.0f};
  const int gstride = gridDim.x * 4;

  int g = blockIdx.x * 4 + wid;
  if (g >= ngroups) return;          // after the barrier: safe

  int   tiL = tix[g * 64 + lane];
  float rh  = rho[g * 64 + lane];

  for (; g < ngroups; g += gstride) {
    const int gbase = g * 64;

    // prefetch next group's point data
    const int gn = (g + gstride < ngroups) ? (g + gstride) : g;
    const int   tiLn = tix[gn * 64 + lane];
    const float rhn  = rho[gn * 64 + lane];

    float dcar = 0.0f;  // raw output dot for point gbase+lane

#pragma unroll
    for (int st = 0; st < 4; ++st) {
      // ---- emb gather in A/B-fragment layout ----
      const int tim  = __shfl(tiL, st * 16 + m, 64);
      const int idxm = min(max(tim - 1, 0), 510);
      const float* erow = emb + (size_t)idxm * 32 + q * 8;
      const f32x4 e0 = *(const f32x4*)erow;
      const f32x4 e1 = *(const f32x4*)(erow + 4);

      // ---- feature fragment, generated in-layout (one Chebyshev chain) ----
      const float rhp = __shfl(rh, st * 16 + m, 64);
      const float rev = 0.5f * rhp;  // v_sin/v_cos take revolutions
      const float c1  = __builtin_amdgcn_cosf(rev);
      const float s1f = __builtin_amdgcn_sinf(rev);
      const float tc  = 2.0f * c1;
      // chain x_k: q==0 -> cos_k, q==1 -> sin_k (same recurrence)
      const float x1v = (q == 0) ? c1 : s1f;
      const float x0v = (q == 0) ? 1.0f : 0.0f;
      const float x2v = tc * x1v - x0v;
      const float x3v = tc * x2v - x1v;
      const float x4v = tc * x3v - x2v;
      const float x5v = tc * x4v - x3v;
      const float x6v = tc * x5v - x4v;
      const float x7v = tc * x6v - x5v;
      const float x8v = tc * x7v - x6v;
      H8 X1;
      X1.v2[0] = pkh(x1v, x2v);
      X1.v2[1] = pkh(x3v, x4v);
      X1.v2[2] = pkh(x5v, x6v);
      X1.v2[3] = pkh(x7v, x8v);
      {
        const half2v z2 = {};
        const half2v pr = pkh(rhp, 1.0f);
        const bool hi = (q >= 2);
        X1.v2[0] = hi ? ((q == 2) ? pr : z2) : X1.v2[0];
        X1.v2[1] = hi ? z2 : X1.v2[1];
        X1.v2[2] = hi ? z2 : X1.v2[2];
        X1.v2[3] = hi ? z2 : X1.v2[3];
      }
      H8 X0;
      X0.v2[0] = pkh(e0[0], e0[1]); X0.v2[1] = pkh(e0[2], e0[3]);
      X0.v2[2] = pkh(e1[0], e1[1]); X0.v2[3] = pkh(e1[2], e1[3]);

      // ---- L0 (transposed): D = W0^T · X^T, weights from LDS ----
      f32x4 acc[4];
#pragma unroll
      for (int t = 0; t < 4; ++t) {
        const half8 wA = *(const half8*)&Wlds0[0][t][lane][0];
        const half8 wB = *(const half8*)&Wlds0[1][t][lane][0];
        f32x4 a = __builtin_amdgcn_mfma_f32_16x16x32_f16(wA, X0.v8, z, 0, 0, 0);
        a = __builtin_amdgcn_mfma_f32_16x16x32_f16(wB, X1.v8, a, 0, 0, 0);
        acc[t] = a;
      }
      // epilogue: lane(m,q) reg r = preact[hidden=t*16+q*4+r][point=st*16+m]
#pragma unroll
      for (int t = 0; t < 4; ++t) {
        float s0, s1v, s2, s3;
        silu2(acc[t][0], acc[t][1], s0, s1v);
        silu2(acc[t][2], acc[t][3], s2, s3);
        H4 hh;
        hh.v2[0] = pkh(s0, s1v);
        hh.v2[1] = pkh(s2, s3);
        *(half4v*)&Hb[m][t * 16 + q * 4] = hh.v4;
      }

      // ---- L1 (untransposed): D = h1 · W1 + b1, weights from LDS ----
      const half8 Y0 = *(const half8*)&Hb[m][q * 8];        // in-order DS: RAW safe
      const half8 Y1 = *(const half8*)&Hb[m][32 + q * 8];
#pragma unroll
      for (int t = 0; t < 4; ++t) {
        const half8 w1A = *(const half8*)&Wlds1[0][t][lane][0];
        const half8 w1B = *(const half8*)&Wlds1[1][t][lane][0];
        const f32x4 binit = {b1n[t], b1n[t], b1n[t], b1n[t]};
        f32x4 a = __builtin_amdgcn_mfma_f32_16x16x32_f16(Y0, w1A, binit, 0, 0, 0);
        a = __builtin_amdgcn_mfma_f32_16x16x32_f16(Y1, w1B, a, 0, 0, 0);
        acc[t] = a;
      }
      // C[point=q*4+r][hidden=t*16+m]: fuse silu + Wout dot in regs
      float dot0 = 0.0f, dot1 = 0.0f, dot2 = 0.0f, dot3 = 0.0f;
#pragma unroll
      for (int t = 0; t < 4; ++t) {
        float s0, s1v, s2, s3;
        silu2(acc[t][0], acc[t][1], s0, s1v);
        silu2(acc[t][2], acc[t][3], s2, s3);
        dot0 = fmaf(s0,  woutm[t], dot0);
        dot1 = fmaf(s1v, woutm[t], dot1);
        dot2 = fmaf(s2,  woutm[t], dot2);
        dot3 = fmaf(s3,  woutm[t], dot3);
      }
      dot0 = row_sum16(dot0);
      dot1 = row_sum16(dot1);
      dot2 = row_sum16(dot2);
      dot3 = row_sum16(dot3);
      // route: value for point st*16+m lives as dots[m&3] in row (m>>2)
      const float dsel = (m & 2) ? ((m & 1) ? dot3 : dot2) : ((m & 1) ? dot1 : dot0);
      const float dg = __shfl(dsel, (m >> 2) * 16 + (m & 3), 64);
      dcar = (q == st) ? dg : dcar;
    }

    // ---- epilogue: one coalesced 256B store per group per wave ----
    const float theta = sigf(dcar + boutBL);
    out[gbase + lane] = (tiL == 0) ? IC_VAL : theta * CSANMAX;

    tiL = tiLn; rh = rhn;
  }
}

extern "C" void kernel_launch(void* const* d_in, const int* in_sizes, int n_in,
                              void* d_out, int out_size, void* d_ws, size_t ws_size,
                              hipStream_t stream) {
  const int*   tix  = (const int*)d_in[0];
  const float* rho  = (const float*)d_in[1];
  const float* emb  = (const float*)d_in[2];
  const float* W0   = (const float*)d_in[3];
  const float* b0   = (const float*)d_in[4];
  const float* W1   = (const float*)d_in[5];
  const float* b1   = (const float*)d_in[6];
  const float* Wout = (const float*)d_in[7];
  const float* bout = (const float*)d_in[8];
  float* outp = (float*)d_out;

  const int n       = in_sizes[0];   // 2,000,000 (divisible by 64)
  const int ngroups = n / 64;        // 31,250 groups of 64 points

  // 4-wave blocks; LDS 25600 B -> 6 blocks/CU -> 24 waves/CU target
  int grid = 1536;
  const int maxg = (ngroups + 3) / 4;
  if (grid > maxg) grid = maxg;
  mlp_kernel<<<dim3(grid), dim3(256), 0, stream>>>(
      tix, rho, emb, W0, b0, W1, b1, Wout, bout, outp, ngroups);
}